// Round 9
// baseline (580.420 us; speedup 1.0000x reference)
//
#include <hip/hip_runtime.h>

#define BB 1024
#define TB 512
#define FB 64
#define NH1 32
#define NH2 16
#define ND1 16
#define ND2 8

// Wavefront-scope fence: runtime-free compiler barrier against LDS motion
// across masked-publish -> read handoffs (single wave: HW is in-order).
#define WAVE_FENCE() __builtin_amdgcn_fence(__ATOMIC_ACQ_REL, "wavefront")

__device__ __forceinline__ float tanh_fast(float v) {
    // tanh(x) = 1 - 2/(e^{2x}+1); exp inf/0 limits give exactly +-1.
    float e = __expf(2.0f * v);
    return fmaf(-2.0f, __builtin_amdgcn_rcpf(e + 1.0f), 1.0f);
}

// DPP row-rotate by compile-time N (1..15 ONLY) within each 16-lane row.
// VALU op, full rate, ZERO DS-pipe cost. N=0 is never instantiated (0x120
// is an invalid DPP encoding — suspected cause of the R8 build failure).
#define DPPF(x, N) __int_as_float(__builtin_amdgcn_update_dpp(                 \
    0, __float_as_int(x), 0x120 + (N), 0xF, 0xF, false))

// Rotation-dot steps. ASTEP0 = identity slot (no DPP). ASTEP(S) for S=1..15.
#define ASTEP0                                                                 \
    {                                                                          \
        acc0 = fmaf(frag0, wq0[0], acc0); acc1 = fmaf(frag1, wq1[0], acc1);    \
        acc2 = fmaf(frag2, wq2[0], acc2); acc3 = fmaf(frag3, wq3[0], acc3);    \
    }
#define ASTEP(S)                                                               \
    {                                                                          \
        float r0_ = DPPF(frag0, S); float r1_ = DPPF(frag1, S);                \
        float r2_ = DPPF(frag2, S); float r3_ = DPPF(frag3, S);                \
        acc0 = fmaf(r0_, wq0[S], acc0); acc1 = fmaf(r1_, wq1[S], acc1);        \
        acc2 = fmaf(r2_, wq2[S], acc2); acc3 = fmaf(r3_, wq3[S], acc3);        \
    }
#define ASTEPS                                                                 \
    ASTEP0    ASTEP(1)  ASTEP(2)  ASTEP(3)  ASTEP(4)  ASTEP(5)  ASTEP(6)      \
    ASTEP(7)  ASTEP(8)  ASTEP(9)  ASTEP(10) ASTEP(11) ASTEP(12) ASTEP(13)     \
    ASTEP(14) ASTEP(15)

// One wave per batch. Lane = (row = lane>>4, r = lane&15).
//  row0: L1 recurrence. frag0,1 = h1[2r],h1[2r+1]; frag2,3 = dups (2nd output).
//  row1: L2, two steps behind. frag0,1 = h1 copy; frag2 = h2[r]; frag3 = 0-wt.
//  rows2,3: xp_{t+1}. frag0..3 = x[t+1][4r..4r+3]; output h = (row-2)*16+r.
// Iteration t computes: h1_t (row0), h2_{t-2} (row1), xp_{t+1} (rows2,3).
// LDS: xpL 2-slot ring (rows23 -> row0), h1L (row0 -> row1). No barriers.
__global__ __attribute__((amdgpu_flat_work_group_size(64, 64)))
           __attribute__((amdgpu_waves_per_eu(1, 1)))
void rnn_dpp_kernel(
    const float* __restrict__ x,
    const float* __restrict__ Wx1, const float* __restrict__ Wh1, const float* __restrict__ b1,
    const float* __restrict__ Wx2, const float* __restrict__ Wh2, const float* __restrict__ b2,
    const float* __restrict__ W3,  const float* __restrict__ b3,
    const float* __restrict__ W4,  const float* __restrict__ b4,
    const float* __restrict__ Wo,  const float* __restrict__ bo,
    float* __restrict__ out)
{
    __shared__ __align__(16) float xpL[2][NH1];  // xp ring: rows2,3 -> row0
    __shared__ __align__(16) float h1L[NH1];     // h1 publish: row0 -> row1
    __shared__ __align__(16) float h2L[NH2];     // head temp
    __shared__ __align__(16) float ysL[ND1];     // head temp

    const int lane = threadIdx.x;
    const int row  = lane >> 4;
    const int r    = lane & 15;
    const int b    = blockIdx.x;

    // ---- DPP direction probe: does row_ror:1 give lane i <- (i+1)&15 ? ----
    const int pr = __builtin_amdgcn_update_dpp(0, r, 0x121, 0xF, 0xF, false);
    const int dj = (pr == ((r + 1) & 15)) ? 1 : 15;   // j16(s) = (r + dj*s)&15

    // ---- pre-rotated weights: slot s pairs with the rotation-by-s value ----
    const int h0o = 2 * r, h1o = 2 * r + 1;                   // row0 outputs
    const int hx  = (row >= 2) ? ((row - 2) * 16 + r) : 0;    // rows2,3 output
    float wq0[16], wq1[16], wq2[16], wq3[16];
#pragma unroll
    for (int s = 0; s < 16; ++s) {
        const int j = (r + dj * s) & 15;
        float a0, a1, a2, a3;
        if (row == 0) {               // Wh1 columns for outputs 2r, 2r+1
            a0 = Wh1[(2 * j) * NH1 + h0o]; a1 = Wh1[(2 * j + 1) * NH1 + h0o];
            a2 = Wh1[(2 * j) * NH1 + h1o]; a3 = Wh1[(2 * j + 1) * NH1 + h1o];
        } else if (row == 1) {        // Wx2 column g=r (slots 0,1), Wh2 (slot 2)
            a0 = Wx2[(2 * j) * NH2 + r];   a1 = Wx2[(2 * j + 1) * NH2 + r];
            a2 = Wh2[j * NH2 + r];         a3 = 0.0f;
        } else {                      // Wx1 column hx, 4 features per slot
            a0 = Wx1[(4 * j + 0) * NH1 + hx]; a1 = Wx1[(4 * j + 1) * NH1 + hx];
            a2 = Wx1[(4 * j + 2) * NH1 + hx]; a3 = Wx1[(4 * j + 3) * NH1 + hx];
        }
        wq0[s] = a0; wq1[s] = a1; wq2[s] = a2; wq3[s] = a3;
    }
    const float init0 = (row >= 2) ? b1[hx] : ((row == 1) ? b2[r] : 0.0f);

    // ---- state + x prefetch queue (rows2,3 only) ----
    float frag0 = 0.0f, frag1 = 0.0f, frag2 = 0.0f, frag3 = 0.0f;
    const float* xB = x + (size_t)b * TB * FB + 4 * r;
    float4 qA = make_float4(0.f, 0.f, 0.f, 0.f);
    float4 qB = qA, qC = qA, qD = qA, fnext = qA;
    if (row >= 2) {
        float4 f0 = *(const float4*)(xB + 0 * FB);
        fnext     = *(const float4*)(xB + 1 * FB);
        qA = *(const float4*)(xB + 2 * FB);
        qB = *(const float4*)(xB + 3 * FB);
        qC = *(const float4*)(xB + 4 * FB);
        qD = *(const float4*)(xB + 5 * FB);
        frag0 = f0.x; frag1 = f0.y; frag2 = f0.z; frag3 = f0.w;
    }
    if (lane < NH1) h1L[lane] = 0.0f;
    WAVE_FENCE();

    // ---- prologue: xp_0 -> slot 0 (rows0,1 results discarded) ----
    {
        float acc0 = init0, acc1 = 0.0f, acc2 = 0.0f, acc3 = 0.0f;
        ASTEPS
        WAVE_FENCE();
        if (row >= 2) {
            xpL[0][hx] = ((acc0 + acc1) + (acc2 + acc3));
            frag0 = fnext.x; frag1 = fnext.y; frag2 = fnext.z; frag3 = fnext.w;
        }
        WAVE_FENCE();
    }

// One iteration. T_ = uniform timestep; PAR_ = T_&1 (compile-time since the
// loop steps by 4); QH_ = this iteration's queue register (x[T_+2], refilled
// with x[T_+6] -> 4 iterations of latency cover).
#define ITER(T_, PAR_, QH_)                                                    \
    {                                                                          \
        float acc0 = init0, acc1 = 0.0f, acc2 = 0.0f, acc3 = 0.0f;             \
        ASTEPS                                                                 \
        const float S1_ = acc0 + acc1;                                         \
        const float S2_ = acc2 + acc3;                                         \
        const float Tv_ = S1_ + S2_;                                           \
        const float2 xv_ = *(const float2*)&xpL[PAR_][2 * r];                  \
        const float u0_ = tanh_fast(S1_ + xv_.x);                              \
        const float u1_ = tanh_fast(S2_ + xv_.y);                              \
        const float uT_ = tanh_fast(Tv_);                                      \
        WAVE_FENCE();                                                          \
        if (row == 1) {   /* C1: grab h1_{t-1} BEFORE row0 writes h1_t */      \
            float2 hp_ = *(const float2*)&h1L[2 * r];                          \
            frag2 = ((T_) >= 2) ? uT_ : 0.0f;                                  \
            frag0 = hp_.x; frag1 = hp_.y;                                      \
        }                                                                      \
        WAVE_FENCE();                                                          \
        if (row == 0) {   /* C2: commit h1_t to regs + publish for row1 */     \
            *(float2*)&h1L[2 * r] = make_float2(u0_, u1_);                     \
            frag0 = u0_; frag1 = u1_; frag2 = u0_; frag3 = u1_;                \
        }                                                                      \
        if (row >= 2) {   /* xp_{t+1} -> other slot; reload frags from queue */\
            xpL[(PAR_) ^ 1][hx] = Tv_;                                         \
            frag0 = QH_.x; frag1 = QH_.y; frag2 = QH_.z; frag3 = QH_.w;        \
            int tn_ = (T_) + 6; tn_ = (tn_ < TB) ? tn_ : (TB - 1);             \
            QH_ = *(const float4*)(xB + (size_t)tn_ * FB);                     \
        }                                                                      \
        WAVE_FENCE();                                                          \
    }

#pragma unroll 1
    for (int t = 0; t < TB; t += 4) {
        ITER(t + 0, 0, qA)
        ITER(t + 1, 1, qB)
        ITER(t + 2, 0, qC)
        ITER(t + 3, 1, qD)
    }
#undef ITER

    // ---- epilogue: two L2-only steps -> h2_510, h2_511 (row1) ----
#pragma unroll 1
    for (int e = 0; e < 2; ++e) {
        float acc0 = init0, acc1 = 0.0f, acc2 = 0.0f, acc3 = 0.0f;
        ASTEPS
        const float uT_ = tanh_fast((acc0 + acc1) + (acc2 + acc3));
        WAVE_FENCE();
        if (row == 1) {
            float2 hp_ = *(const float2*)&h1L[2 * r];
            frag2 = uT_;             // h2_{510}, then h2_{511}
            frag0 = hp_.x; frag1 = hp_.y;   // h1_{511} both times
        }
        WAVE_FENCE();
    }

    // ---- dense head (R0-proven scalar form) ----
    if (row == 1) h2L[r] = frag2;
    WAVE_FENCE();

    const int g = lane & 15;
    float a3h = b3[g];
#pragma unroll
    for (int j = 0; j < 16; ++j) a3h = fmaf(h2L[j], W3[j * ND1 + g], a3h);
    float y1 = fmaxf(a3h, 0.0f);
    WAVE_FENCE();
    if (lane < ND1) ysL[lane] = y1;
    WAVE_FENCE();

    const int e = lane & 7;
    float a4 = b4[e];
#pragma unroll
    for (int j = 0; j < 16; ++j) a4 = fmaf(ysL[j], W4[j * ND2 + e], a4);

    float yo = a4 * Wo[e];
    yo += __shfl_xor(yo, 1, 64);
    yo += __shfl_xor(yo, 2, 64);
    yo += __shfl_xor(yo, 4, 64);
    if (lane == 0) out[b] = yo + bo[0];
}

extern "C" void kernel_launch(void* const* d_in, const int* in_sizes, int n_in,
                              void* d_out, int out_size, void* d_ws, size_t ws_size,
                              hipStream_t stream) {
    const float* x   = (const float*)d_in[0];
    const float* Wx1 = (const float*)d_in[1];
    const float* Wh1 = (const float*)d_in[2];
    const float* b1  = (const float*)d_in[3];
    const float* Wx2 = (const float*)d_in[4];
    const float* Wh2 = (const float*)d_in[5];
    const float* b2  = (const float*)d_in[6];
    const float* W3  = (const float*)d_in[7];
    const float* b3  = (const float*)d_in[8];
    const float* W4  = (const float*)d_in[9];
    const float* b4  = (const float*)d_in[10];
    const float* Wo  = (const float*)d_in[11];
    const float* bo  = (const float*)d_in[12];
    float* out = (float*)d_out;

    rnn_dpp_kernel<<<dim3(BB), dim3(64), 0, stream>>>(
        x, Wx1, Wh1, b1, Wx2, Wh2, b2, W3, b3, W4, b4, Wo, bo, out);
}

// Round 10
// 546.782 us; speedup vs baseline: 1.0615x; 1.0615x over previous
//
#include <hip/hip_runtime.h>

#define BB 1024
#define TB 512
#define FB 64
#define NH1 32
#define NH2 16
#define ND1 16
#define ND2 8

#define RD 16              // ring depth in steps (2 chunks)
#define RDM (RD - 1)
#define CHUNK 8            // steps per barrier period
#define NCH (TB / CHUNK)   // 64 chunks

// Wavefront-scope fence: runtime-free compiler barrier against LDS motion
// across masked-publish -> read handoffs.
#define WAVE_FENCE() __builtin_amdgcn_fence(__ATOMIC_ACQ_REL, "wavefront")

__device__ __forceinline__ float tanh_fast(float v) {
    // tanh(x) = 1 - 2/(e^{2x}+1); exp inf/0 limits give exactly +-1.
    float e = __expf(2.0f * v);
    return fmaf(-2.0f, __builtin_amdgcn_rcpf(e + 1.0f), 1.0f);
}

// DPP row-rotate by compile-time N (1..15 ONLY; 0x120 is invalid). VALU op,
// zero DS-pipe cost. Direction probed at runtime, folded into weight order.
// Scheme hardware-verified in R9 (absmax = 0).
#define DPPF(x, N) __int_as_float(__builtin_amdgcn_update_dpp(                 \
    0, __float_as_int(x), 0x120 + (N), 0xF, 0xF, false))

// 3 waves per block, uniform barrier schedule (proven R2/R3/R5/R6):
//   iter c: wave0 -> xp chunk c | wave1 -> L1 chunk c-1 | wave2 -> L2 chunk
//   c-2; then ONE __syncthreads(). NCH+2 iterations for every wave -> equal
//   barrier counts -> no deadlock.
// R3 was DS-throughput-bound (~900 cy/step/CU). This version moves xp (wave0)
// and L2 (wave2) onto the VALU pipe via R9's verified DPP rotation schemes,
// keeping only wave1's L1 on cheap LDS broadcasts: DS ~30 ops/step/CU (~250
// cy), VALU ~390 cy/step/SIMD -> issue-bound.
__global__ __attribute__((amdgpu_flat_work_group_size(192, 192)))
           __attribute__((amdgpu_waves_per_eu(3)))
void rnn_pipe_kernel(
    const float* __restrict__ x,
    const float* __restrict__ Wx1, const float* __restrict__ Wh1, const float* __restrict__ b1,
    const float* __restrict__ Wx2, const float* __restrict__ Wh2, const float* __restrict__ b2,
    const float* __restrict__ W3,  const float* __restrict__ b3,
    const float* __restrict__ W4,  const float* __restrict__ b4,
    const float* __restrict__ Wo,  const float* __restrict__ bo,
    float* __restrict__ out)
{
    __shared__ __align__(16) float xpring[RD][NH1];  // xp (b1 folded): w0 -> w1
    __shared__ __align__(16) float h1ring[RD][NH1];  // h1: w1 -> w1/w2
    __shared__ __align__(16) float h2L[NH2];         // head temp (w2 only)
    __shared__ __align__(16) float ysL[ND1];         // head temp (w2 only)

    const int tid  = threadIdx.x;
    const int wid  = tid >> 6;
    const int lane = tid & 63;
    const int r    = lane & 15;
    const int b    = blockIdx.x;

    // DPP direction probe (uniform result; verified R9).
    const int pr = __builtin_amdgcn_update_dpp(0, r, 0x121, 0xF, 0xF, false);
    const int dj = (pr == ((r + 1) & 15)) ? 1 : 15;   // j(s) = (r + dj*s)&15

    if (wid == 0) {
        // ====== wave 0: xp producer — DPP rotation dot (R9 rows2,3) =========
        // Lane (row = lane>>4, r): computes xp[t][hx], hx = ((row&1)<<4)|r,
        // t = tbase + (row>>1)  (rows 0,1 -> even step; rows 2,3 -> odd).
        // frag = x[t][4r..4r+3] per-lane float4 (coalesced 256B per row-pair),
        // 16 rotation slots x 4 FMA = full 64-dot. One b32 ring write / 2 steps.
        const int trow = lane >> 5;                 // t offset (0/1)
        const int hx   = ((lane >> 4) & 1) * 16 + r;
        float wq0[16], wq1[16], wq2[16], wq3[16];
#pragma unroll
        for (int s = 0; s < 16; ++s) {
            const int j = (r + dj * s) & 15;
            wq0[s] = Wx1[(4 * j + 0) * NH1 + hx];
            wq1[s] = Wx1[(4 * j + 1) * NH1 + hx];
            wq2[s] = Wx1[(4 * j + 2) * NH1 + hx];
            wq3[s] = Wx1[(4 * j + 3) * NH1 + hx];
        }
        const float b1v = b1[hx];
        const float* xBs = x + (size_t)b * TB * FB + 4 * r + (size_t)trow * FB;

// Chunk prefetch: 4 float4 per lane (passes 0..3), clamped for the tail.
#define PFQ(R0, R1, R2, R3, CN)                                                \
    {                                                                          \
        const int bs_ = (CN) * CHUNK; int tq_;                                 \
        tq_ = bs_ + 0; tq_ = (tq_ <= TB-2) ? tq_ : (TB-2);                     \
        R0 = *(const float4*)(xBs + (size_t)tq_ * FB);                         \
        tq_ = bs_ + 2; tq_ = (tq_ <= TB-2) ? tq_ : (TB-2);                     \
        R1 = *(const float4*)(xBs + (size_t)tq_ * FB);                         \
        tq_ = bs_ + 4; tq_ = (tq_ <= TB-2) ? tq_ : (TB-2);                     \
        R2 = *(const float4*)(xBs + (size_t)tq_ * FB);                         \
        tq_ = bs_ + 6; tq_ = (tq_ <= TB-2) ? tq_ : (TB-2);                     \
        R3 = *(const float4*)(xBs + (size_t)tq_ * FB);                         \
    }

#define XS(S)                                                                  \
    { float r0_ = DPPF(f0, S); float r1_ = DPPF(f1, S);                        \
      float r2_ = DPPF(f2, S); float r3_ = DPPF(f3, S);                        \
      acc0 = fmaf(r0_, wq0[S], acc0); acc1 = fmaf(r1_, wq1[S], acc1);          \
      acc2 = fmaf(r2_, wq2[S], acc2); acc3 = fmaf(r3_, wq3[S], acc3); }

// One pass = 2 timesteps (row-pairs). TB0_ = uniform even t base.
#define XPPASS(Q, TB0_)                                                        \
    {                                                                          \
        float f0 = Q.x, f1 = Q.y, f2 = Q.z, f3 = Q.w;                          \
        float acc0 = b1v, acc1 = 0.0f, acc2 = 0.0f, acc3 = 0.0f;               \
        acc0 = fmaf(f0, wq0[0], acc0); acc1 = fmaf(f1, wq1[0], acc1);          \
        acc2 = fmaf(f2, wq2[0], acc2); acc3 = fmaf(f3, wq3[0], acc3);          \
        XS(1)  XS(2)  XS(3)  XS(4)  XS(5)  XS(6)  XS(7)  XS(8)                 \
        XS(9)  XS(10) XS(11) XS(12) XS(13) XS(14) XS(15)                       \
        WAVE_FENCE();                                                          \
        xpring[((TB0_) + trow) & RDM][hx] = (acc0 + acc1) + (acc2 + acc3);     \
    }

        float4 qa0, qa1, qa2, qa3, qb0, qb1, qb2, qb3;
        PFQ(qa0, qa1, qa2, qa3, 0);   // chunk 0

#pragma unroll 1
        for (int c = 0; c < NCH + 2; ++c) {
            if (c < NCH) {
                const int t0 = c * CHUNK;
                if ((c & 1) == 0) {
                    PFQ(qb0, qb1, qb2, qb3, c + 1);
                    XPPASS(qa0, t0 + 0) XPPASS(qa1, t0 + 2)
                    XPPASS(qa2, t0 + 4) XPPASS(qa3, t0 + 6)
                } else {
                    PFQ(qa0, qa1, qa2, qa3, c + 1);
                    XPPASS(qb0, t0 + 0) XPPASS(qb1, t0 + 2)
                    XPPASS(qb2, t0 + 4) XPPASS(qb3, t0 + 6)
                }
            }
            __syncthreads();
        }
#undef XPPASS
#undef XS
#undef PFQ

    } else if (wid == 1) {
        // ====== wave 1: L1 recurrence — R0's verified split-half scheme =====
        // Lane (h = lane&31, p = lane>>5): half-dot from 4 b128 broadcast
        // reads of h1ring, xp added in p==0 only, shfl_xor(32) combine.
        const int h = lane & 31;
        const int p = lane >> 5;
        auto r1f = [&](int i) { return Wh1[(16 * p + i) * NH1 + h]; };
        const float4 wha = make_float4(r1f(0),  r1f(1),  r1f(2),  r1f(3));
        const float4 whb = make_float4(r1f(4),  r1f(5),  r1f(6),  r1f(7));
        const float4 whc = make_float4(r1f(8),  r1f(9),  r1f(10), r1f(11));
        const float4 whd = make_float4(r1f(12), r1f(13), r1f(14), r1f(15));

        if (p == 0) h1ring[RDM][h] = 0.0f;   // h1_{-1} = 0 (slot (0-1)&15)

#define L1S(T)                                                                 \
    {                                                                          \
        const int t_ = (T);                                                    \
        float xpv = xpring[t_ & RDM][h];                                       \
        const float4* hr = (const float4*)&h1ring[(t_ - 1) & RDM][16 * p];     \
        float4 hva = hr[0], hvb = hr[1], hvc = hr[2], hvd = hr[3];             \
        float a0 = (p == 0) ? xpv : 0.0f;                                      \
        float a1 = 0.0f, a2 = 0.0f, a3 = 0.0f;                                 \
        a0 = fmaf(hva.x, wha.x, a0); a1 = fmaf(hva.y, wha.y, a1);              \
        a2 = fmaf(hva.z, wha.z, a2); a3 = fmaf(hva.w, wha.w, a3);              \
        a0 = fmaf(hvb.x, whb.x, a0); a1 = fmaf(hvb.y, whb.y, a1);              \
        a2 = fmaf(hvb.z, whb.z, a2); a3 = fmaf(hvb.w, whb.w, a3);              \
        a0 = fmaf(hvc.x, whc.x, a0); a1 = fmaf(hvc.y, whc.y, a1);              \
        a2 = fmaf(hvc.z, whc.z, a2); a3 = fmaf(hvc.w, whc.w, a3);              \
        a0 = fmaf(hvd.x, whd.x, a0); a1 = fmaf(hvd.y, whd.y, a1);              \
        a2 = fmaf(hvd.z, whd.z, a2); a3 = fmaf(hvd.w, whd.w, a3);              \
        float acc = (a0 + a1) + (a2 + a3);                                     \
        acc += __shfl_xor(acc, 32, 64);                                        \
        float h1new = tanh_fast(acc);                                          \
        WAVE_FENCE();                                                          \
        if (p == 0) h1ring[t_ & RDM][h] = h1new;                               \
        WAVE_FENCE();                                                          \
    }

#pragma unroll 1
        for (int c = 0; c < NCH + 2; ++c) {
            if (c >= 1 && c <= NCH) {
                const int t0 = (c - 1) * CHUNK;
                L1S(t0 + 0) L1S(t0 + 1) L1S(t0 + 2) L1S(t0 + 3)
                L1S(t0 + 4) L1S(t0 + 5) L1S(t0 + 6) L1S(t0 + 7)
            }
            __syncthreads();
        }
#undef L1S

    } else {
        // ====== wave 2: L2 recurrence — R9-row1's verified DPP scheme =======
        // Lane r (&15; rows duplicate): f0,f1 = h1[2r],h1[2r+1] (one float2
        // LDS read, batched per chunk), f2 = h2[r] register-resident.
        // 16 rotation slots x 3 FMA = full (h1@Wx2 + h2@Wh2) dot per lane.
        float w20[16], w21[16], w22[16];
#pragma unroll
        for (int s = 0; s < 16; ++s) {
            const int j = (r + dj * s) & 15;
            w20[s] = Wx2[(2 * j) * NH2 + r];
            w21[s] = Wx2[(2 * j + 1) * NH2 + r];
            w22[s] = Wh2[j * NH2 + r];
        }
        const float b2v = b2[r];
        float h2v = 0.0f;   // h2_{-1} = 0

#define YS(S)                                                                  \
    { float r0_ = DPPF(f0, S); float r1_ = DPPF(f1, S);                        \
      float r2_ = DPPF(f2, S);                                                 \
      acc0 = fmaf(r0_, w20[S], acc0); acc1 = fmaf(r1_, w21[S], acc1);          \
      acc2 = fmaf(r2_, w22[S], acc2); }

#define L2S(HP)                                                                \
    {                                                                          \
        float f0 = HP.x, f1 = HP.y, f2 = h2v;                                  \
        float acc0 = b2v, acc1 = 0.0f, acc2 = 0.0f;                            \
        acc0 = fmaf(f0, w20[0], acc0); acc1 = fmaf(f1, w21[0], acc1);          \
        acc2 = fmaf(f2, w22[0], acc2);                                         \
        YS(1)  YS(2)  YS(3)  YS(4)  YS(5)  YS(6)  YS(7)  YS(8)                 \
        YS(9)  YS(10) YS(11) YS(12) YS(13) YS(14) YS(15)                       \
        h2v = tanh_fast((acc0 + acc1) + acc2);                                 \
    }

#pragma unroll 1
        for (int c = 0; c < NCH + 2; ++c) {
            if (c >= 2) {
                const int t2 = (c - 2) * CHUNK;
                // batch the 8 h1 float2 reads up front (off the h2 chain)
                float2 hp0 = *(const float2*)&h1ring[(t2 + 0) & RDM][2 * r];
                float2 hp1 = *(const float2*)&h1ring[(t2 + 1) & RDM][2 * r];
                float2 hp2 = *(const float2*)&h1ring[(t2 + 2) & RDM][2 * r];
                float2 hp3 = *(const float2*)&h1ring[(t2 + 3) & RDM][2 * r];
                float2 hp4 = *(const float2*)&h1ring[(t2 + 4) & RDM][2 * r];
                float2 hp5 = *(const float2*)&h1ring[(t2 + 5) & RDM][2 * r];
                float2 hp6 = *(const float2*)&h1ring[(t2 + 6) & RDM][2 * r];
                float2 hp7 = *(const float2*)&h1ring[(t2 + 7) & RDM][2 * r];
                L2S(hp0) L2S(hp1) L2S(hp2) L2S(hp3)
                L2S(hp4) L2S(hp5) L2S(hp6) L2S(hp7)
            }
            __syncthreads();
        }
#undef L2S
#undef YS

        // ---- dense head (R3-verified scalar form) ----
        WAVE_FENCE();
        if (lane < NH2) h2L[lane] = h2v;   // lanes 0..15 hold h2[r]
        WAVE_FENCE();

        const int g = lane & 15;
        float a3h = b3[g];
#pragma unroll
        for (int j = 0; j < 16; ++j) a3h = fmaf(h2L[j], W3[j * ND1 + g], a3h);
        float y1 = fmaxf(a3h, 0.0f);
        WAVE_FENCE();
        if (lane < ND1) ysL[lane] = y1;
        WAVE_FENCE();

        const int e = lane & 7;
        float a4 = b4[e];
#pragma unroll
        for (int j = 0; j < 16; ++j) a4 = fmaf(ysL[j], W4[j * ND2 + e], a4);

        float yo = a4 * Wo[e];
        yo += __shfl_xor(yo, 1, 64);
        yo += __shfl_xor(yo, 2, 64);
        yo += __shfl_xor(yo, 4, 64);
        if (lane == 0) out[b] = yo + bo[0];
    }
}

extern "C" void kernel_launch(void* const* d_in, const int* in_sizes, int n_in,
                              void* d_out, int out_size, void* d_ws, size_t ws_size,
                              hipStream_t stream) {
    const float* x   = (const float*)d_in[0];
    const float* Wx1 = (const float*)d_in[1];
    const float* Wh1 = (const float*)d_in[2];
    const float* b1  = (const float*)d_in[3];
    const float* Wx2 = (const float*)d_in[4];
    const float* Wh2 = (const float*)d_in[5];
    const float* b2  = (const float*)d_in[6];
    const float* W3  = (const float*)d_in[7];
    const float* b3  = (const float*)d_in[8];
    const float* W4  = (const float*)d_in[9];
    const float* b4  = (const float*)d_in[10];
    const float* Wo  = (const float*)d_in[11];
    const float* bo  = (const float*)d_in[12];
    float* out = (float*)d_out;

    rnn_pipe_kernel<<<dim3(BB), dim3(192), 0, stream>>>(
        x, Wx1, Wh1, b1, Wx2, Wh2, b2, W3, b3, W4, b4, Wo, bo, out);
}

// Round 11
// 299.782 us; speedup vs baseline: 1.9361x; 1.8239x over previous
//
#include <hip/hip_runtime.h>

#define BB 1024
#define TB 512
#define FB 64
#define NH1 32
#define NH2 16
#define ND1 16
#define ND2 8

#define CHUNK 16           // steps per barrier period
#define NCH (TB / CHUNK)   // 32 chunks
#define RD 32              // ring depth in steps (2 chunks)
#define RDM (RD - 1)

// Wavefront-scope fence: compiler barrier against LDS motion across
// masked-publish -> read handoffs (DS pipe is in-order per wave).
#define WAVE_FENCE() __builtin_amdgcn_fence(__ATOMIC_ACQ_REL, "wavefront")

// Pin a value into a VGPR: opaque redefinition the compiler cannot
// rematerialize. Fixes the R3/R6/R10 pathology where hipcc re-loaded the
// weight matrices from global memory inside every timestep (VGPR_Count 36!).
#define PIN4(v) asm volatile("" : "+v"((v).x), "+v"((v).y), "+v"((v).z), "+v"((v).w))
#define PIN1(s) asm volatile("" : "+v"(s))

__device__ __forceinline__ float tanh_fast(float v) {
    // tanh(x) = 1 - 2/(e^{2x}+1); exp inf/0 limits give exactly +-1.
    float e = __expf(2.0f * v);
    return fmaf(-2.0f, __builtin_amdgcn_rcpf(e + 1.0f), 1.0f);
}

// 3 waves per block, uniform barrier schedule (structure proven R2/R3/R5/R6):
//   iter c: wave0 stages x chunk c + computes xp-low chunk c-1
//           wave1 runs L1 chunk c-2
//           wave2 computes xp-high chunk c-1 + L2 chunk c-3
//   then ONE __syncthreads(). All waves run NCH+3 iterations -> equal barrier
//   counts -> no deadlock.
// xp split: wave0 covers features 32p+0..23 (b1 folded), wave2 covers
// 32p+24..31; raw per-lane partials in P0/P1 rings; wave1 gathers 2 scalars
// and the shfl_xor(32) combine sums all four quadrants.
__global__ __attribute__((amdgpu_flat_work_group_size(192, 192)))
           __attribute__((amdgpu_waves_per_eu(3)))
void rnn_pipe_kernel(
    const float* __restrict__ x,
    const float* __restrict__ Wx1, const float* __restrict__ Wh1, const float* __restrict__ b1,
    const float* __restrict__ Wx2, const float* __restrict__ Wh2, const float* __restrict__ b2,
    const float* __restrict__ W3,  const float* __restrict__ b3,
    const float* __restrict__ W4,  const float* __restrict__ b4,
    const float* __restrict__ Wo,  const float* __restrict__ bo,
    float* __restrict__ out)
{
    __shared__ __align__(16) float xs[2][CHUNK][FB];  // x stage, dbuf (8 KB)
    __shared__ __align__(16) float P0ring[RD][64];    // xp-low raw partials (8 KB)
    __shared__ __align__(16) float P1ring[RD][64];    // xp-high raw partials (8 KB)
    __shared__ __align__(16) float h1ring[RD][NH1];   // h1: w1 -> w1/w2 (4 KB)
    __shared__ __align__(16) float h2L[NH2];          // h2 state (w2 only)
    __shared__ __align__(16) float ysL[ND1];          // head temp (w2 only)

    const int tid  = threadIdx.x;
    const int wid  = tid >> 6;
    const int lane = tid & 63;
    const int h = lane & 31;   // output unit (L1 space)
    const int p = lane >> 5;   // half flag
    const int g = lane & 15;   // L2 output unit
    const int q = lane >> 4;   // L2 quarter
    const int b = blockIdx.x;

    if (wid == 0) {
        // ===== wave 0: x staging + xp features 32p+0..23 =====================
        auto w1f = [&](int i) { return Wx1[(32 * p + i) * NH1 + h]; };
        float4 wx0 = make_float4(w1f(0),  w1f(1),  w1f(2),  w1f(3));
        float4 wx1 = make_float4(w1f(4),  w1f(5),  w1f(6),  w1f(7));
        float4 wx2 = make_float4(w1f(8),  w1f(9),  w1f(10), w1f(11));
        float4 wx3 = make_float4(w1f(12), w1f(13), w1f(14), w1f(15));
        float4 wx4 = make_float4(w1f(16), w1f(17), w1f(18), w1f(19));
        float4 wx5 = make_float4(w1f(20), w1f(21), w1f(22), w1f(23));
        float b1v = (p == 0) ? b1[h] : 0.0f;
        PIN4(wx0); PIN4(wx1); PIN4(wx2); PIN4(wx3); PIN4(wx4); PIN4(wx5);
        PIN1(b1v);

        const float* xb = x + (size_t)b * TB * FB + lane;   // lane = feature
        float q0,q1,q2,q3,q4,q5,q6,q7,q8,q9,q10,q11,q12,q13,q14,q15;

#define LOADQ(CN)                                                              \
    { const int t0_ = (CN) * CHUNK;                                            \
      q0  = xb[(size_t)(t0_ +  0) * FB]; q1  = xb[(size_t)(t0_ +  1) * FB];    \
      q2  = xb[(size_t)(t0_ +  2) * FB]; q3  = xb[(size_t)(t0_ +  3) * FB];    \
      q4  = xb[(size_t)(t0_ +  4) * FB]; q5  = xb[(size_t)(t0_ +  5) * FB];    \
      q6  = xb[(size_t)(t0_ +  6) * FB]; q7  = xb[(size_t)(t0_ +  7) * FB];    \
      q8  = xb[(size_t)(t0_ +  8) * FB]; q9  = xb[(size_t)(t0_ +  9) * FB];    \
      q10 = xb[(size_t)(t0_ + 10) * FB]; q11 = xb[(size_t)(t0_ + 11) * FB];    \
      q12 = xb[(size_t)(t0_ + 12) * FB]; q13 = xb[(size_t)(t0_ + 13) * FB];    \
      q14 = xb[(size_t)(t0_ + 14) * FB]; q15 = xb[(size_t)(t0_ + 15) * FB]; }

#define STAGE(BUF)                                                             \
    { xs[BUF][ 0][lane] = q0;  xs[BUF][ 1][lane] = q1;                         \
      xs[BUF][ 2][lane] = q2;  xs[BUF][ 3][lane] = q3;                         \
      xs[BUF][ 4][lane] = q4;  xs[BUF][ 5][lane] = q5;                         \
      xs[BUF][ 6][lane] = q6;  xs[BUF][ 7][lane] = q7;                         \
      xs[BUF][ 8][lane] = q8;  xs[BUF][ 9][lane] = q9;                         \
      xs[BUF][10][lane] = q10; xs[BUF][11][lane] = q11;                        \
      xs[BUF][12][lane] = q12; xs[BUF][13][lane] = q13;                        \
      xs[BUF][14][lane] = q14; xs[BUF][15][lane] = q15; }

#define XPL(S, T0, CB)                                                         \
    {                                                                          \
        const float4* xv = (const float4*)&xs[CB][S][32 * p];                  \
        float a0 = b1v, a1 = 0.0f, a2 = 0.0f, a3 = 0.0f;                       \
        float4 v_;                                                             \
        v_ = xv[0]; a0 = fmaf(v_.x, wx0.x, a0); a1 = fmaf(v_.y, wx0.y, a1);    \
                    a2 = fmaf(v_.z, wx0.z, a2); a3 = fmaf(v_.w, wx0.w, a3);    \
        v_ = xv[1]; a0 = fmaf(v_.x, wx1.x, a0); a1 = fmaf(v_.y, wx1.y, a1);    \
                    a2 = fmaf(v_.z, wx1.z, a2); a3 = fmaf(v_.w, wx1.w, a3);    \
        v_ = xv[2]; a0 = fmaf(v_.x, wx2.x, a0); a1 = fmaf(v_.y, wx2.y, a1);    \
                    a2 = fmaf(v_.z, wx2.z, a2); a3 = fmaf(v_.w, wx2.w, a3);    \
        v_ = xv[3]; a0 = fmaf(v_.x, wx3.x, a0); a1 = fmaf(v_.y, wx3.y, a1);    \
                    a2 = fmaf(v_.z, wx3.z, a2); a3 = fmaf(v_.w, wx3.w, a3);    \
        v_ = xv[4]; a0 = fmaf(v_.x, wx4.x, a0); a1 = fmaf(v_.y, wx4.y, a1);    \
                    a2 = fmaf(v_.z, wx4.z, a2); a3 = fmaf(v_.w, wx4.w, a3);    \
        v_ = xv[5]; a0 = fmaf(v_.x, wx5.x, a0); a1 = fmaf(v_.y, wx5.y, a1);    \
                    a2 = fmaf(v_.z, wx5.z, a2); a3 = fmaf(v_.w, wx5.w, a3);    \
        P0ring[((T0) + (S)) & RDM][lane] = (a0 + a1) + (a2 + a3);              \
    }

        LOADQ(0);
#pragma unroll 1
        for (int c = 0; c < NCH + 3; ++c) {
            if (c < NCH) {
                STAGE(c & 1);
                if (c + 1 < NCH) LOADQ(c + 1);
            }
            if (c >= 1 && c <= NCH) {
                const int t0 = (c - 1) * CHUNK;
                const int cb = (c - 1) & 1;
                XPL( 0, t0, cb) XPL( 1, t0, cb) XPL( 2, t0, cb) XPL( 3, t0, cb)
                XPL( 4, t0, cb) XPL( 5, t0, cb) XPL( 6, t0, cb) XPL( 7, t0, cb)
                XPL( 8, t0, cb) XPL( 9, t0, cb) XPL(10, t0, cb) XPL(11, t0, cb)
                XPL(12, t0, cb) XPL(13, t0, cb) XPL(14, t0, cb) XPL(15, t0, cb)
            }
            __syncthreads();
        }
#undef XPL
#undef STAGE
#undef LOADQ

    } else if (wid == 1) {
        // ===== wave 1: L1 recurrence (split-half, R0-proven math) ===========
        auto r1f = [&](int i) { return Wh1[(16 * p + i) * NH1 + h]; };
        float4 wha = make_float4(r1f(0),  r1f(1),  r1f(2),  r1f(3));
        float4 whb = make_float4(r1f(4),  r1f(5),  r1f(6),  r1f(7));
        float4 whc = make_float4(r1f(8),  r1f(9),  r1f(10), r1f(11));
        float4 whd = make_float4(r1f(12), r1f(13), r1f(14), r1f(15));
        PIN4(wha); PIN4(whb); PIN4(whc); PIN4(whd);

        if (p == 0) h1ring[RDM][h] = 0.0f;   // h1_{-1} = 0 (slot (0-1)&31)
        const int xoff = h + 32 * p;         // raw-partial gather index

#define L1S(T)                                                                 \
    {                                                                          \
        const int t_ = (T);                                                    \
        float xpA = P0ring[t_ & RDM][xoff];                                    \
        float xpB = P1ring[t_ & RDM][xoff];                                    \
        const float4* hr = (const float4*)&h1ring[(t_ - 1) & RDM][16 * p];     \
        float4 hva = hr[0], hvb = hr[1], hvc = hr[2], hvd = hr[3];             \
        float a0 = xpA + xpB, a1 = 0.0f, a2 = 0.0f, a3 = 0.0f;                 \
        a0 = fmaf(hva.x, wha.x, a0); a1 = fmaf(hva.y, wha.y, a1);              \
        a2 = fmaf(hva.z, wha.z, a2); a3 = fmaf(hva.w, wha.w, a3);              \
        a0 = fmaf(hvb.x, whb.x, a0); a1 = fmaf(hvb.y, whb.y, a1);              \
        a2 = fmaf(hvb.z, whb.z, a2); a3 = fmaf(hvb.w, whb.w, a3);              \
        a0 = fmaf(hvc.x, whc.x, a0); a1 = fmaf(hvc.y, whc.y, a1);              \
        a2 = fmaf(hvc.z, whc.z, a2); a3 = fmaf(hvc.w, whc.w, a3);              \
        a0 = fmaf(hvd.x, whd.x, a0); a1 = fmaf(hvd.y, whd.y, a1);              \
        a2 = fmaf(hvd.z, whd.z, a2); a3 = fmaf(hvd.w, whd.w, a3);              \
        float acc = (a0 + a1) + (a2 + a3);                                     \
        acc += __shfl_xor(acc, 32, 64);                                        \
        float h1new = tanh_fast(acc);                                          \
        WAVE_FENCE();                                                          \
        if (p == 0) h1ring[t_ & RDM][h] = h1new;                               \
        WAVE_FENCE();                                                          \
    }

#pragma unroll 1
        for (int c = 0; c < NCH + 3; ++c) {
            if (c >= 2 && c <= NCH + 1) {
                const int t0 = (c - 2) * CHUNK;
                L1S(t0 +  0) L1S(t0 +  1) L1S(t0 +  2) L1S(t0 +  3)
                L1S(t0 +  4) L1S(t0 +  5) L1S(t0 +  6) L1S(t0 +  7)
                L1S(t0 +  8) L1S(t0 +  9) L1S(t0 + 10) L1S(t0 + 11)
                L1S(t0 + 12) L1S(t0 + 13) L1S(t0 + 14) L1S(t0 + 15)
            }
            __syncthreads();
        }
#undef L1S

    } else {
        // ===== wave 2: xp features 32p+24..31 + L2 (quarter-split) + head ===
        auto w1f = [&](int i) { return Wx1[(32 * p + 24 + i) * NH1 + h]; };
        float4 wy0 = make_float4(w1f(0), w1f(1), w1f(2), w1f(3));
        float4 wy1 = make_float4(w1f(4), w1f(5), w1f(6), w1f(7));
        auto w2f = [&](int i) { return Wx2[(8 * q + i) * NH2 + g]; };
        float4 o2a = make_float4(w2f(0), w2f(1), w2f(2), w2f(3));
        float4 o2b = make_float4(w2f(4), w2f(5), w2f(6), w2f(7));
        auto r2f = [&](int i) { return Wh2[(4 * q + i) * NH2 + g]; };
        float4 h2w = make_float4(r2f(0), r2f(1), r2f(2), r2f(3));
        float b2v = (q == 0) ? b2[g] : 0.0f;
        PIN4(wy0); PIN4(wy1); PIN4(o2a); PIN4(o2b); PIN4(h2w); PIN1(b2v);

        if (lane < NH2) h2L[lane] = 0.0f;

#define XPH(S, T0, CB)                                                         \
    {                                                                          \
        const float4* xv = (const float4*)&xs[CB][S][32 * p + 24];             \
        float a0 = 0.0f, a1 = 0.0f, a2 = 0.0f, a3 = 0.0f;                      \
        float4 v_;                                                             \
        v_ = xv[0]; a0 = fmaf(v_.x, wy0.x, a0); a1 = fmaf(v_.y, wy0.y, a1);    \
                    a2 = fmaf(v_.z, wy0.z, a2); a3 = fmaf(v_.w, wy0.w, a3);    \
        v_ = xv[1]; a0 = fmaf(v_.x, wy1.x, a0); a1 = fmaf(v_.y, wy1.y, a1);    \
                    a2 = fmaf(v_.z, wy1.z, a2); a3 = fmaf(v_.w, wy1.w, a3);    \
        P1ring[((T0) + (S)) & RDM][lane] = (a0 + a1) + (a2 + a3);              \
    }

#define L2S(T)                                                                 \
    {                                                                          \
        const int t_ = (T);                                                    \
        const float* hrow = &h1ring[t_ & RDM][8 * q];                          \
        float4 u0 = *(const float4*)(hrow);                                    \
        float4 u1 = *(const float4*)(hrow + 4);                                \
        float4 hw = *(const float4*)&h2L[4 * q];                               \
        float c0 = b2v, c1 = 0.0f;                                             \
        c0 = fmaf(u0.x, o2a.x, c0); c1 = fmaf(u0.y, o2a.y, c1);                \
        c0 = fmaf(u0.z, o2a.z, c0); c1 = fmaf(u0.w, o2a.w, c1);                \
        c0 = fmaf(u1.x, o2b.x, c0); c1 = fmaf(u1.y, o2b.y, c1);                \
        c0 = fmaf(u1.z, o2b.z, c0); c1 = fmaf(u1.w, o2b.w, c1);                \
        c0 = fmaf(hw.x, h2w.x, c0); c1 = fmaf(hw.y, h2w.y, c1);                \
        c0 = fmaf(hw.z, h2w.z, c0); c1 = fmaf(hw.w, h2w.w, c1);                \
        float cc = c0 + c1;                                                    \
        cc += __shfl_xor(cc, 16, 64);                                          \
        cc += __shfl_xor(cc, 32, 64);                                          \
        float h2new = tanh_fast(cc);                                           \
        WAVE_FENCE();                                                          \
        if (lane < NH2) h2L[lane] = h2new;                                     \
        WAVE_FENCE();                                                          \
    }

#pragma unroll 1
        for (int c = 0; c < NCH + 3; ++c) {
            if (c >= 1 && c <= NCH) {
                const int t0 = (c - 1) * CHUNK;
                const int cb = (c - 1) & 1;
                XPH( 0, t0, cb) XPH( 1, t0, cb) XPH( 2, t0, cb) XPH( 3, t0, cb)
                XPH( 4, t0, cb) XPH( 5, t0, cb) XPH( 6, t0, cb) XPH( 7, t0, cb)
                XPH( 8, t0, cb) XPH( 9, t0, cb) XPH(10, t0, cb) XPH(11, t0, cb)
                XPH(12, t0, cb) XPH(13, t0, cb) XPH(14, t0, cb) XPH(15, t0, cb)
            }
            if (c >= 3) {
                const int t2 = (c - 3) * CHUNK;
                L2S(t2 +  0) L2S(t2 +  1) L2S(t2 +  2) L2S(t2 +  3)
                L2S(t2 +  4) L2S(t2 +  5) L2S(t2 +  6) L2S(t2 +  7)
                L2S(t2 +  8) L2S(t2 +  9) L2S(t2 + 10) L2S(t2 + 11)
                L2S(t2 + 12) L2S(t2 + 13) L2S(t2 + 14) L2S(t2 + 15)
            }
            __syncthreads();
        }
#undef XPH
#undef L2S

        // ---- dense head (R0-proven scalar form; wave2 only) ----
        WAVE_FENCE();
        float a3h = b3[g];
#pragma unroll
        for (int j = 0; j < 16; ++j) a3h = fmaf(h2L[j], W3[j * ND1 + g], a3h);
        float y1 = fmaxf(a3h, 0.0f);
        WAVE_FENCE();
        if (lane < ND1) ysL[lane] = y1;
        WAVE_FENCE();

        const int e = lane & 7;
        float a4 = b4[e];
#pragma unroll
        for (int j = 0; j < 16; ++j) a4 = fmaf(ysL[j], W4[j * ND2 + e], a4);

        float yo = a4 * Wo[e];
        yo += __shfl_xor(yo, 1, 64);
        yo += __shfl_xor(yo, 2, 64);
        yo += __shfl_xor(yo, 4, 64);
        if (lane == 0) out[b] = yo + bo[0];
    }
}

extern "C" void kernel_launch(void* const* d_in, const int* in_sizes, int n_in,
                              void* d_out, int out_size, void* d_ws, size_t ws_size,
                              hipStream_t stream) {
    const float* x   = (const float*)d_in[0];
    const float* Wx1 = (const float*)d_in[1];
    const float* Wh1 = (const float*)d_in[2];
    const float* b1  = (const float*)d_in[3];
    const float* Wx2 = (const float*)d_in[4];
    const float* Wh2 = (const float*)d_in[5];
    const float* b2  = (const float*)d_in[6];
    const float* W3  = (const float*)d_in[7];
    const float* b3  = (const float*)d_in[8];
    const float* W4  = (const float*)d_in[9];
    const float* b4  = (const float*)d_in[10];
    const float* Wo  = (const float*)d_in[11];
    const float* bo  = (const float*)d_in[12];
    float* out = (float*)d_out;

    rnn_pipe_kernel<<<dim3(BB), dim3(192), 0, stream>>>(
        x, Wx1, Wh1, b1, Wx2, Wh2, b2, W3, b3, W4, b4, Wo, bo, out);
}